// Round 3
// baseline (1773.579 us; speedup 1.0000x reference)
//
#include <hip/hip_runtime.h>
#include <math.h>

#define NPTS 8192
#define DIM  64
#define NCH  4        // j-chunks per job
#define JCH  2048     // NPTS / NCH
#define NRB  64       // NPTS / 128 row blocks
#define JT   16       // JCH / 128 j-iters per block
#define LSYH 72       // y LDS row stride in halfwords (64 + 8 pad = 144 B)
#define NPART 8       // NCH * 2 wave-cols partials per row

static const float LN2_ = 0.69314718055994530942f;

typedef _Float16 f16x8 __attribute__((ext_vector_type(8)));
typedef float    f32x4 __attribute__((ext_vector_type(4)));

__device__ __forceinline__ float fexp2(float x) {
#if __has_builtin(__builtin_amdgcn_exp2f)
    return __builtin_amdgcn_exp2f(x);
#else
    return exp2f(x);
#endif
}

// 0.5*|row|^2 for x and y (fp32)
__global__ void norms_kernel(const float* __restrict__ x, const float* __restrict__ y,
                             float* __restrict__ x2h, float* __restrict__ y2h) {
    int i = blockIdx.x * blockDim.x + threadIdx.x;   // 0 .. 2*NPTS-1
    const float* src = (i < NPTS) ? x : y;
    float* dst = (i < NPTS) ? x2h : y2h;
    int r = (i < NPTS) ? i : i - NPTS;
    const float4* p = (const float4*)(src + (size_t)r * DIM);
    float s = 0.f;
#pragma unroll
    for (int k = 0; k < DIM / 4; ++k) {
        float4 v = p[k];
        s += v.x * v.x + v.y * v.y + v.z * v.z + v.w * v.w;
    }
    dst[r] = 0.5f * s;
}

// fp32 -> fp16 conversion (one-time per call), 8 elements/thread
__global__ void convert_kernel(const float* __restrict__ x, const float* __restrict__ y,
                               _Float16* __restrict__ xh, _Float16* __restrict__ yh) {
    int i = blockIdx.x * 256 + threadIdx.x;          // 0 .. 2*NPTS*DIM/8 - 1
    int e = i * 8;
    const float* src; _Float16* dst; int off;
    if (e < NPTS * DIM) { src = x; dst = xh; off = e; }
    else                { src = y; dst = yh; off = e - NPTS * DIM; }
    float4 a = *(const float4*)(src + off);
    float4 b = *(const float4*)(src + off + 4);
    f16x8 o = { (_Float16)a.x, (_Float16)a.y, (_Float16)a.z, (_Float16)a.w,
                (_Float16)b.x, (_Float16)b.y, (_Float16)b.z, (_Float16)b.w };
    *(f16x8*)(dst + off) = o;
}

// MFMA-based fused softmin. 4 jobs per launch (blockIdx.y):
//  jb=0: rows=x over y (g=g_ab)   jb=1: rows=y over x (g=f_ba)
//  jb=2: rows=x over x (g=f_aa)   jb=3: rows=y over y (g=g_bb)
// Per-row partial (m,s) in base-2 logit space, excluding -0.5|x_i|^2/eps.
// launch_bounds(256,4): 4 blocks/CU (16/32 waves). VGPR=88, LDS=26.6KB -> fits.
__launch_bounds__(256, 4)
__global__ void softmin_kernel(const _Float16* __restrict__ xh, const _Float16* __restrict__ yh,
                               const float* __restrict__ x2h, const float* __restrict__ y2h,
                               const float* __restrict__ g_ab, const float* __restrict__ f_ba,
                               const float* __restrict__ f_aa, const float* __restrict__ g_bb,
                               float* __restrict__ partials,
                               float inv_eps, int use_g) {
    const int jb = blockIdx.y;
    const int rb = blockIdx.x / NCH;
    const int ch = blockIdx.x % NCH;

    const _Float16* X; const _Float16* Y; const float* g; const float* ynorm;
    if (jb == 0)      { X = xh; Y = yh; g = g_ab; ynorm = y2h; }
    else if (jb == 1) { X = yh; Y = xh; g = f_ba; ynorm = x2h; }
    else if (jb == 2) { X = xh; Y = xh; g = f_aa; ynorm = x2h; }
    else              { X = yh; Y = yh; g = g_bb; ynorm = y2h; }

    __shared__ _Float16 ys[128 * LSYH];   // 18432 B
    __shared__ float hys[JCH];            //  8192 B

    const int t = threadIdx.x;
    const int wave = t >> 6, lane = t & 63;
    const int wr = wave >> 1, wc = wave & 1;
    const int l15 = lane & 15, quad = lane >> 4;

    const float base = -9.0109131783f;               // -ln(8192)
    const float L2E  = 1.44269504089f;
    const float inv2 = inv_eps * L2E;                // log2e / eps

    // per-column fold: hy_j = log2e*h_log[j] - 0.5|y_j|^2 * log2e/eps
    for (int j = t; j < JCH; j += 256) {
        int jj = ch * JCH + j;
        float hl = base;
        if (use_g) hl += g[jj] * inv_eps;
        hys[j] = L2E * hl - ynorm[jj] * inv2;
    }

    // A fragments for the whole K=64, resident in registers for the block's life
    const int i0 = rb * 128 + wr * 64;
    f16x8 af[4][2];
#pragma unroll
    for (int u = 0; u < 4; ++u)
#pragma unroll
        for (int h = 0; h < 2; ++h)
            af[u][h] = *(const f16x8*)(X + ((size_t)(i0 + u * 16 + l15)) * DIM + h * 32 + quad * 8);

    // register prefetch of y-tile jt=0
    const int srow = t >> 3, skc = t & 7;            // thread's (row,kchunk) base
    f16x8 pre[4];
#pragma unroll
    for (int c = 0; c < 4; ++c)
        pre[c] = *(const f16x8*)(Y + ((size_t)ch * JCH + (srow + c * 32)) * DIM + skc * 8);

    float m[16], s[16];
#pragma unroll
    for (int u = 0; u < 16; ++u) { m[u] = -3.0e38f; s[u] = 0.f; }

    for (int jt = 0; jt < JT; ++jt) {
        __syncthreads();                              // prior iter's ys reads done
#pragma unroll
        for (int c = 0; c < 4; ++c)
            *(f16x8*)&ys[(srow + c * 32) * LSYH + skc * 8] = pre[c];
        __syncthreads();

        // prefetch next tile (clamped on last iter; covered by compute below)
        {
            int jn = (jt + 1 < JT) ? jt + 1 : jt;
            const _Float16* srcY = Y + ((size_t)ch * JCH + (size_t)jn * 128) * DIM;
#pragma unroll
            for (int c = 0; c < 4; ++c)
                pre[c] = *(const f16x8*)(srcY + (srow + c * 32) * DIM + skc * 8);
        }

        // B fragments from LDS
        f16x8 bf[4][2];
#pragma unroll
        for (int v = 0; v < 4; ++v)
#pragma unroll
            for (int h = 0; h < 2; ++h)
                bf[v][h] = *(const f16x8*)&ys[(wc * 64 + v * 16 + l15) * LSYH + h * 32 + quad * 8];

        f32x4 acc[4][4];
#pragma unroll
        for (int u = 0; u < 4; ++u)
#pragma unroll
            for (int v = 0; v < 4; ++v) {
                f32x4 z = {0.f, 0.f, 0.f, 0.f};
                z = __builtin_amdgcn_mfma_f32_16x16x32_f16(af[u][0], bf[v][0], z, 0, 0, 0);
                acc[u][v] = __builtin_amdgcn_mfma_f32_16x16x32_f16(af[u][1], bf[v][1], z, 0, 0, 0);
            }

        // online base-2 logsumexp epilogue
        float hvv[4];
#pragma unroll
        for (int v = 0; v < 4; ++v)
            hvv[v] = hys[jt * 128 + wc * 64 + v * 16 + l15];

#pragma unroll
        for (int u = 0; u < 4; ++u)
#pragma unroll
            for (int r = 0; r < 4; ++r) {
                int idx = u * 4 + r;
                float w0 = fmaf(acc[u][0][r], inv2, hvv[0]);
                float w1 = fmaf(acc[u][1][r], inv2, hvv[1]);
                float w2 = fmaf(acc[u][2][r], inv2, hvv[2]);
                float w3 = fmaf(acc[u][3][r], inv2, hvv[3]);
                float mn = fmaxf(fmaxf(fmaxf(w0, w1), fmaxf(w2, w3)), m[idx]);
                float e0 = fexp2(w0 - mn), e1 = fexp2(w1 - mn);
                float e2 = fexp2(w2 - mn), e3 = fexp2(w3 - mn);
                s[idx] = fmaf(s[idx], fexp2(m[idx] - mn), (e0 + e1) + (e2 + e3));
                m[idx] = mn;
            }
    }

    // combine across the 16 lane-columns (lane bits 0..3)
#pragma unroll
    for (int st = 1; st <= 8; st <<= 1) {
#pragma unroll
        for (int u = 0; u < 16; ++u) {
            float mo = __shfl_xor(m[u], st, 64);
            float so = __shfl_xor(s[u], st, 64);
            float M = fmaxf(m[u], mo);
            s[u] = s[u] * fexp2(m[u] - M) + so * fexp2(mo - M);
            m[u] = M;
        }
    }
    if (l15 == 0) {
        int p = ch * 2 + wc;
#pragma unroll
        for (int u = 0; u < 4; ++u)
#pragma unroll
            for (int r = 0; r < 4; ++r) {
                int row = i0 + u * 16 + quad * 4 + r;
                size_t off = (((size_t)jb * NPART + p) * NPTS + row) * 2;
                partials[off]     = m[u * 4 + r];
                partials[off + 1] = s[u * 4 + r];
            }
    }
}

// combine NPART partials per row -> f_i = 0.5|x_i|^2 - eps*ln2*(M + log2 s);
// avg mode implements pot = 0.5*(pot_old + f_new)
__global__ void combine_kernel(const float* __restrict__ partials,
                               const float* __restrict__ x2h, const float* __restrict__ y2h,
                               float* __restrict__ o0, float* __restrict__ o1,
                               float* __restrict__ o2, float* __restrict__ o3,
                               float eps, int avg) {
    int jb = blockIdx.y;
    int i = blockIdx.x * 256 + threadIdx.x;
    const float* xn = (jb == 0 || jb == 2) ? x2h : y2h;
    float* out = (jb == 0) ? o0 : (jb == 1) ? o1 : (jb == 2) ? o2 : o3;

    float mv[NPART], sv[NPART];
    float M = -3.0e38f;
#pragma unroll
    for (int p = 0; p < NPART; ++p) {
        size_t off = (((size_t)jb * NPART + p) * NPTS + i) * 2;
        mv[p] = partials[off];
        sv[p] = partials[off + 1];
        M = fmaxf(M, mv[p]);
    }
    float st = 0.f;
#pragma unroll
    for (int p = 0; p < NPART; ++p) st += sv[p] * fexp2(mv[p] - M);
    float val = xn[i] - eps * LN2_ * (M + __log2f(st));
    if (avg) val = 0.5f * (out[i] + val);
    out[i] = val;
}

__global__ void reduce_kernel(const float* __restrict__ fba, const float* __restrict__ gab,
                              const float* __restrict__ faa, const float* __restrict__ gbb,
                              float* __restrict__ out) {
    __shared__ float red[256];
    int t = threadIdx.x;
    float s = 0.f;
    for (int i = t; i < NPTS; i += 256)
        s += (fba[i] - faa[i]) + (gab[i] - gbb[i]);
    red[t] = s;
    __syncthreads();
    for (int st = 128; st > 0; st >>= 1) {
        if (t < st) red[t] += red[t + st];
        __syncthreads();
    }
    if (t == 0) out[0] = red[0] / (float)NPTS;
}

extern "C" void kernel_launch(void* const* d_in, const int* in_sizes, int n_in,
                              void* d_out, int out_size, void* d_ws, size_t ws_size,
                              hipStream_t stream) {
    const float* x = (const float*)d_in[0];
    const float* y = (const float*)d_in[1];
    float* ws = (float*)d_ws;

    float* x2h   = ws + 0 * NPTS;
    float* y2h   = ws + 1 * NPTS;
    float* f_ba  = ws + 2 * NPTS;
    float* g_ab  = ws + 3 * NPTS;
    float* f_aa  = ws + 4 * NPTS;
    float* g_bb  = ws + 5 * NPTS;
    float* fba_f = ws + 6 * NPTS;
    float* gab_f = ws + 7 * NPTS;
    float* faa_f = ws + 8 * NPTS;
    float* gbb_f = ws + 9 * NPTS;
    float* partials = ws + 10 * NPTS;                   // 4*8*NPTS*2 = 64*NPTS floats
    _Float16* xh = (_Float16*)(ws + 74 * NPTS);         // NPTS*DIM halves = 32*NPTS floats
    _Float16* yh = xh + (size_t)NPTS * DIM;             // total ws use: 138*NPTS floats

    const float EPS[11] = {1024.f, 256.f, 64.f, 16.f, 4.f, 1.f,
                           0.25f, 0.0625f, 0.015625f, 0.00390625f, 0.0025f};

    norms_kernel<<<dim3(2 * NPTS / 256), dim3(256), 0, stream>>>(x, y, x2h, y2h);
    convert_kernel<<<dim3(2 * NPTS * DIM / 8 / 256), dim3(256), 0, stream>>>(x, y, xh, yh);

    dim3 sgrid(NRB * NCH, 4), sblk(256);
    dim3 cgrid(NPTS / 256, 4), cblk(256);

    // init: 4 softmins at eps0 with constant h (g unused), plain write
    softmin_kernel<<<sgrid, sblk, 0, stream>>>(xh, yh, x2h, y2h, g_ab, f_ba, f_aa, g_bb,
                                               partials, 1.f / EPS[0], 0);
    combine_kernel<<<cgrid, cblk, 0, stream>>>(partials, x2h, y2h,
                                               f_ba, g_ab, f_aa, g_bb, EPS[0], 0);

    // epsilon-scaling loop with symmetric averaged updates
    for (int it = 0; it < 11; ++it) {
        softmin_kernel<<<sgrid, sblk, 0, stream>>>(xh, yh, x2h, y2h, g_ab, f_ba, f_aa, g_bb,
                                                   partials, 1.f / EPS[it], 1);
        combine_kernel<<<cgrid, cblk, 0, stream>>>(partials, x2h, y2h,
                                                   f_ba, g_ab, f_aa, g_bb, EPS[it], 1);
    }

    // final non-averaged extrapolation at eps = blur^2
    softmin_kernel<<<sgrid, sblk, 0, stream>>>(xh, yh, x2h, y2h, g_ab, f_ba, f_aa, g_bb,
                                               partials, 1.f / EPS[10], 1);
    combine_kernel<<<cgrid, cblk, 0, stream>>>(partials, x2h, y2h,
                                               fba_f, gab_f, faa_f, gbb_f, EPS[10], 0);

    reduce_kernel<<<1, 256, 0, stream>>>(fba_f, gab_f, faa_f, gbb_f, (float*)d_out);
}

// Round 4
// 1014.886 us; speedup vs baseline: 1.7476x; 1.7476x over previous
//
#include <hip/hip_runtime.h>
#include <math.h>

#define NPTS 8192
#define DIM  64
#define NCH  4        // j-chunks per job
#define JCH  2048     // NPTS / NCH
#define NRB  64       // NPTS / 128 row blocks
#define JT   16       // JCH / 128 j-iters per block
#define LSYH 72       // y LDS row stride in halfwords (64 + 8 pad = 144 B)
#define NPART 8       // NCH * 2 wave-cols partials per row

static const float LN2_ = 0.69314718055994530942f;

typedef _Float16 f16x8 __attribute__((ext_vector_type(8)));
typedef float    f32x4 __attribute__((ext_vector_type(4)));

__device__ __forceinline__ float fexp2(float x) {
#if __has_builtin(__builtin_amdgcn_exp2f)
    return __builtin_amdgcn_exp2f(x);
#else
    return exp2f(x);
#endif
}

// 0.5*|row|^2 for x and y (fp32)
__global__ void norms_kernel(const float* __restrict__ x, const float* __restrict__ y,
                             float* __restrict__ x2h, float* __restrict__ y2h) {
    int i = blockIdx.x * blockDim.x + threadIdx.x;   // 0 .. 2*NPTS-1
    const float* src = (i < NPTS) ? x : y;
    float* dst = (i < NPTS) ? x2h : y2h;
    int r = (i < NPTS) ? i : i - NPTS;
    const float4* p = (const float4*)(src + (size_t)r * DIM);
    float s = 0.f;
#pragma unroll
    for (int k = 0; k < DIM / 4; ++k) {
        float4 v = p[k];
        s += v.x * v.x + v.y * v.y + v.z * v.z + v.w * v.w;
    }
    dst[r] = 0.5f * s;
}

// fp32 -> fp16 conversion (one-time per call), 8 elements/thread
__global__ void convert_kernel(const float* __restrict__ x, const float* __restrict__ y,
                               _Float16* __restrict__ xh, _Float16* __restrict__ yh) {
    int i = blockIdx.x * 256 + threadIdx.x;          // 0 .. 2*NPTS*DIM/8 - 1
    int e = i * 8;
    const float* src; _Float16* dst; int off;
    if (e < NPTS * DIM) { src = x; dst = xh; off = e; }
    else                { src = y; dst = yh; off = e - NPTS * DIM; }
    float4 a = *(const float4*)(src + off);
    float4 b = *(const float4*)(src + off + 4);
    f16x8 o = { (_Float16)a.x, (_Float16)a.y, (_Float16)a.z, (_Float16)a.w,
                (_Float16)b.x, (_Float16)b.y, (_Float16)b.z, (_Float16)b.w };
    *(f16x8*)(dst + off) = o;
}

// MFMA-based fused softmin. 4 jobs per launch (blockIdx.y):
//  jb=0: rows=x over y (g=g_ab)   jb=1: rows=y over x (g=f_ba)
//  jb=2: rows=x over x (g=f_aa)   jb=3: rows=y over y (g=g_bb)
// Per-row partial (m,s) in base-2 logit space, excluding -0.5|x_i|^2/eps.
// NOTE (R3 post-mortem): launch_bounds reg cap covers VGPR+AGPR combined on
// gfx950 (unified file). (256,4) forced 64 regs -> acc spilled to scratch
// (196+152 MB/dispatch HBM!). Epilogue is u-sliced so acc live range is 16
// regs, total ~110; (256,3) caps at 168 = safe, 4 blocks/CU if alloc <= 128.
__launch_bounds__(256, 3)
__global__ void softmin_kernel(const _Float16* __restrict__ xh, const _Float16* __restrict__ yh,
                               const float* __restrict__ x2h, const float* __restrict__ y2h,
                               const float* __restrict__ g_ab, const float* __restrict__ f_ba,
                               const float* __restrict__ f_aa, const float* __restrict__ g_bb,
                               float* __restrict__ partials,
                               float inv_eps, int use_g) {
    const int jb = blockIdx.y;
    const int rb = blockIdx.x / NCH;
    const int ch = blockIdx.x % NCH;

    const _Float16* X; const _Float16* Y; const float* g; const float* ynorm;
    if (jb == 0)      { X = xh; Y = yh; g = g_ab; ynorm = y2h; }
    else if (jb == 1) { X = yh; Y = xh; g = f_ba; ynorm = x2h; }
    else if (jb == 2) { X = xh; Y = xh; g = f_aa; ynorm = x2h; }
    else              { X = yh; Y = yh; g = g_bb; ynorm = y2h; }

    __shared__ _Float16 ys[128 * LSYH];   // 18432 B
    __shared__ float hys[JCH];            //  8192 B

    const int t = threadIdx.x;
    const int wave = t >> 6, lane = t & 63;
    const int wr = wave >> 1, wc = wave & 1;
    const int l15 = lane & 15, quad = lane >> 4;

    const float base = -9.0109131783f;               // -ln(8192)
    const float L2E  = 1.44269504089f;
    const float inv2 = inv_eps * L2E;                // log2e / eps

    // per-column fold: hy_j = log2e*h_log[j] - 0.5|y_j|^2 * log2e/eps
    for (int j = t; j < JCH; j += 256) {
        int jj = ch * JCH + j;
        float hl = base;
        if (use_g) hl += g[jj] * inv_eps;
        hys[j] = L2E * hl - ynorm[jj] * inv2;
    }

    // A fragments for the whole K=64, resident in registers for the block's life
    const int i0 = rb * 128 + wr * 64;
    f16x8 af[4][2];
#pragma unroll
    for (int u = 0; u < 4; ++u)
#pragma unroll
        for (int h = 0; h < 2; ++h)
            af[u][h] = *(const f16x8*)(X + ((size_t)(i0 + u * 16 + l15)) * DIM + h * 32 + quad * 8);

    // register prefetch of y-tile jt=0
    const int srow = t >> 3, skc = t & 7;            // thread's (row,kchunk) base
    f16x8 pre[4];
#pragma unroll
    for (int c = 0; c < 4; ++c)
        pre[c] = *(const f16x8*)(Y + ((size_t)ch * JCH + (srow + c * 32)) * DIM + skc * 8);

    float m[16], s[16];
#pragma unroll
    for (int u = 0; u < 16; ++u) { m[u] = -3.0e38f; s[u] = 0.f; }

    for (int jt = 0; jt < JT; ++jt) {
        __syncthreads();                              // prior iter's ys reads done
#pragma unroll
        for (int c = 0; c < 4; ++c)
            *(f16x8*)&ys[(srow + c * 32) * LSYH + skc * 8] = pre[c];
        __syncthreads();

        // prefetch next tile (clamped on last iter; covered by compute below)
        {
            int jn = (jt + 1 < JT) ? jt + 1 : jt;
            const _Float16* srcY = Y + ((size_t)ch * JCH + (size_t)jn * 128) * DIM;
#pragma unroll
            for (int c = 0; c < 4; ++c)
                pre[c] = *(const f16x8*)(srcY + (srow + c * 32) * DIM + skc * 8);
        }

        // B fragments from LDS
        f16x8 bf[4][2];
#pragma unroll
        for (int v = 0; v < 4; ++v)
#pragma unroll
            for (int h = 0; h < 2; ++h)
                bf[v][h] = *(const f16x8*)&ys[(wc * 64 + v * 16 + l15) * LSYH + h * 32 + quad * 8];

        float hvv[4];
#pragma unroll
        for (int v = 0; v < 4; ++v)
            hvv[v] = hys[jt * 128 + wc * 64 + v * 16 + l15];

        // u-sliced: 8 MFMAs for one row-group, then its epilogue.
        // Keeps acc live range at 16 regs (was 64 -> reg-bound occupancy).
#pragma unroll
        for (int u = 0; u < 4; ++u) {
            f32x4 acc[4];
#pragma unroll
            for (int v = 0; v < 4; ++v) {
                f32x4 z = {0.f, 0.f, 0.f, 0.f};
                z = __builtin_amdgcn_mfma_f32_16x16x32_f16(af[u][0], bf[v][0], z, 0, 0, 0);
                acc[v] = __builtin_amdgcn_mfma_f32_16x16x32_f16(af[u][1], bf[v][1], z, 0, 0, 0);
            }
#pragma unroll
            for (int r = 0; r < 4; ++r) {
                int idx = u * 4 + r;
                float w0 = fmaf(acc[0][r], inv2, hvv[0]);
                float w1 = fmaf(acc[1][r], inv2, hvv[1]);
                float w2 = fmaf(acc[2][r], inv2, hvv[2]);
                float w3 = fmaf(acc[3][r], inv2, hvv[3]);
                float mn = fmaxf(fmaxf(fmaxf(w0, w1), fmaxf(w2, w3)), m[idx]);
                float e0 = fexp2(w0 - mn), e1 = fexp2(w1 - mn);
                float e2 = fexp2(w2 - mn), e3 = fexp2(w3 - mn);
                s[idx] = fmaf(s[idx], fexp2(m[idx] - mn), (e0 + e1) + (e2 + e3));
                m[idx] = mn;
            }
        }
    }

    // combine across the 16 lane-columns (lane bits 0..3)
#pragma unroll
    for (int st = 1; st <= 8; st <<= 1) {
#pragma unroll
        for (int u = 0; u < 16; ++u) {
            float mo = __shfl_xor(m[u], st, 64);
            float so = __shfl_xor(s[u], st, 64);
            float M = fmaxf(m[u], mo);
            s[u] = s[u] * fexp2(m[u] - M) + so * fexp2(mo - M);
            m[u] = M;
        }
    }
    if (l15 == 0) {
        int p = ch * 2 + wc;
#pragma unroll
        for (int u = 0; u < 4; ++u)
#pragma unroll
            for (int r = 0; r < 4; ++r) {
                int row = i0 + u * 16 + quad * 4 + r;
                size_t off = (((size_t)jb * NPART + p) * NPTS + row) * 2;
                partials[off]     = m[u * 4 + r];
                partials[off + 1] = s[u * 4 + r];
            }
    }
}

// combine NPART partials per row -> f_i = 0.5|x_i|^2 - eps*ln2*(M + log2 s);
// avg mode implements pot = 0.5*(pot_old + f_new)
__global__ void combine_kernel(const float* __restrict__ partials,
                               const float* __restrict__ x2h, const float* __restrict__ y2h,
                               float* __restrict__ o0, float* __restrict__ o1,
                               float* __restrict__ o2, float* __restrict__ o3,
                               float eps, int avg) {
    int jb = blockIdx.y;
    int i = blockIdx.x * 256 + threadIdx.x;
    const float* xn = (jb == 0 || jb == 2) ? x2h : y2h;
    float* out = (jb == 0) ? o0 : (jb == 1) ? o1 : (jb == 2) ? o2 : o3;

    float mv[NPART], sv[NPART];
    float M = -3.0e38f;
#pragma unroll
    for (int p = 0; p < NPART; ++p) {
        size_t off = (((size_t)jb * NPART + p) * NPTS + i) * 2;
        mv[p] = partials[off];
        sv[p] = partials[off + 1];
        M = fmaxf(M, mv[p]);
    }
    float st = 0.f;
#pragma unroll
    for (int p = 0; p < NPART; ++p) st += sv[p] * fexp2(mv[p] - M);
    float val = xn[i] - eps * LN2_ * (M + __log2f(st));
    if (avg) val = 0.5f * (out[i] + val);
    out[i] = val;
}

__global__ void reduce_kernel(const float* __restrict__ fba, const float* __restrict__ gab,
                              const float* __restrict__ faa, const float* __restrict__ gbb,
                              float* __restrict__ out) {
    __shared__ float red[256];
    int t = threadIdx.x;
    float s = 0.f;
    for (int i = t; i < NPTS; i += 256)
        s += (fba[i] - faa[i]) + (gab[i] - gbb[i]);
    red[t] = s;
    __syncthreads();
    for (int st = 128; st > 0; st >>= 1) {
        if (t < st) red[t] += red[t + st];
        __syncthreads();
    }
    if (t == 0) out[0] = red[0] / (float)NPTS;
}

extern "C" void kernel_launch(void* const* d_in, const int* in_sizes, int n_in,
                              void* d_out, int out_size, void* d_ws, size_t ws_size,
                              hipStream_t stream) {
    const float* x = (const float*)d_in[0];
    const float* y = (const float*)d_in[1];
    float* ws = (float*)d_ws;

    float* x2h   = ws + 0 * NPTS;
    float* y2h   = ws + 1 * NPTS;
    float* f_ba  = ws + 2 * NPTS;
    float* g_ab  = ws + 3 * NPTS;
    float* f_aa  = ws + 4 * NPTS;
    float* g_bb  = ws + 5 * NPTS;
    float* fba_f = ws + 6 * NPTS;
    float* gab_f = ws + 7 * NPTS;
    float* faa_f = ws + 8 * NPTS;
    float* gbb_f = ws + 9 * NPTS;
    float* partials = ws + 10 * NPTS;                   // 4*8*NPTS*2 = 64*NPTS floats
    _Float16* xh = (_Float16*)(ws + 74 * NPTS);         // NPTS*DIM halves = 32*NPTS floats
    _Float16* yh = xh + (size_t)NPTS * DIM;             // total ws use: 138*NPTS floats

    const float EPS[11] = {1024.f, 256.f, 64.f, 16.f, 4.f, 1.f,
                           0.25f, 0.0625f, 0.015625f, 0.00390625f, 0.0025f};

    norms_kernel<<<dim3(2 * NPTS / 256), dim3(256), 0, stream>>>(x, y, x2h, y2h);
    convert_kernel<<<dim3(2 * NPTS * DIM / 8 / 256), dim3(256), 0, stream>>>(x, y, xh, yh);

    dim3 sgrid(NRB * NCH, 4), sblk(256);
    dim3 cgrid(NPTS / 256, 4), cblk(256);

    // init: 4 softmins at eps0 with constant h (g unused), plain write
    softmin_kernel<<<sgrid, sblk, 0, stream>>>(xh, yh, x2h, y2h, g_ab, f_ba, f_aa, g_bb,
                                               partials, 1.f / EPS[0], 0);
    combine_kernel<<<cgrid, cblk, 0, stream>>>(partials, x2h, y2h,
                                               f_ba, g_ab, f_aa, g_bb, EPS[0], 0);

    // epsilon-scaling loop with symmetric averaged updates
    for (int it = 0; it < 11; ++it) {
        softmin_kernel<<<sgrid, sblk, 0, stream>>>(xh, yh, x2h, y2h, g_ab, f_ba, f_aa, g_bb,
                                                   partials, 1.f / EPS[it], 1);
        combine_kernel<<<cgrid, cblk, 0, stream>>>(partials, x2h, y2h,
                                                   f_ba, g_ab, f_aa, g_bb, EPS[it], 1);
    }

    // final non-averaged extrapolation at eps = blur^2
    softmin_kernel<<<sgrid, sblk, 0, stream>>>(xh, yh, x2h, y2h, g_ab, f_ba, f_aa, g_bb,
                                               partials, 1.f / EPS[10], 1);
    combine_kernel<<<cgrid, cblk, 0, stream>>>(partials, x2h, y2h,
                                               fba_f, gab_f, faa_f, gbb_f, EPS[10], 0);

    reduce_kernel<<<1, 256, 0, stream>>>(fba_f, gab_f, faa_f, gbb_f, (float*)d_out);
}